// Round 1
// baseline (60.179 us; speedup 1.0000x reference)
//
#include <hip/hip_runtime.h>

// SequentialSparsemax: (8, 16, 262144) f32.
// pass1: sparsemax over 16 instruments at every (b, t).
// pass2: sparsemax over each 64-sample frame per (b, inst).
// Fully fused: one wave handles a (16 inst x 256 time) tile = 4 frames.
//   phase1: lane = 4 time positions (float4), serial sort-16 per column.
//   phase2: LDS transpose (XOR-swizzled), lane = one (inst, frame) row,
//           serial sort-64, compute tau only.
//   phase3: bpermute taus back to phase-1 layout, coalesced float4 stores.

#define T_DIM   262144
#define N_INST  16
#define B_DIM   8
#define CHUNK   256                   // time samples per wave (4 frames)
#define NCHUNK  (T_DIM / CHUNK)       // 1024

// One bitonic stage; K,S compile-time so `desc` folds and all indices are
// constants after unroll (registers, no scratch).
template<int N, int K, int S>
__device__ __forceinline__ void bstage(float (&a)[N]) {
#pragma unroll
  for (int i = 0; i < N; ++i) {
    const int l = i ^ S;
    if (l > i) {
      const float x = a[i], y = a[l];
      const float hi = fmaxf(x, y), lo = fminf(x, y);
      const bool desc = ((i & K) == 0);
      a[i] = desc ? hi : lo;
      a[l] = desc ? lo : hi;
    }
  }
}

__device__ __forceinline__ void sort_desc16(float (&a)[16]) {
  bstage<16, 2, 1>(a);
  bstage<16, 4, 2>(a);  bstage<16, 4, 1>(a);
  bstage<16, 8, 4>(a);  bstage<16, 8, 2>(a);  bstage<16, 8, 1>(a);
  bstage<16, 16, 8>(a); bstage<16, 16, 4>(a); bstage<16, 16, 2>(a); bstage<16, 16, 1>(a);
}

__device__ __forceinline__ void sort_desc64(float (&a)[64]) {
  bstage<64, 2, 1>(a);
  bstage<64, 4, 2>(a);   bstage<64, 4, 1>(a);
  bstage<64, 8, 4>(a);   bstage<64, 8, 2>(a);   bstage<64, 8, 1>(a);
  bstage<64, 16, 8>(a);  bstage<64, 16, 4>(a);  bstage<64, 16, 2>(a);  bstage<64, 16, 1>(a);
  bstage<64, 32, 16>(a); bstage<64, 32, 8>(a);  bstage<64, 32, 4>(a);  bstage<64, 32, 2>(a);  bstage<64, 32, 1>(a);
  bstage<64, 64, 32>(a); bstage<64, 64, 16>(a); bstage<64, 64, 8>(a);  bstage<64, 64, 4>(a);  bstage<64, 64, 2>(a);  bstage<64, 64, 1>(a);
}

// z must be sorted descending. Mirrors the reference exactly:
// support_k = 1 + (k+1)*z_k > cs_k (prefix-true); tau = (cs_{k*} - 1)/k*.
template<int N>
__device__ __forceinline__ float sparsemax_tau(const float (&z)[N]) {
  float cs = 0.0f, cs_sel = 0.0f, k_sel = 1.0f;
#pragma unroll
  for (int k = 0; k < N; ++k) {
    cs += z[k];
    const bool sup = fmaf((float)(k + 1), z[k], 1.0f) > cs;
    k_sel = sup ? (float)(k + 1) : k_sel;
    cs_sel = sup ? cs : cs_sel;
  }
  return (cs_sel - 1.0f) / k_sel;
}

__global__ __launch_bounds__(64) void seq_sparsemax_kernel(
    const float* __restrict__ in, float* __restrict__ out) {
  __shared__ float tile[N_INST * CHUNK];  // 16 KiB

  const int lane  = threadIdx.x;          // 0..63
  const int b     = blockIdx.x >> 10;     // / NCHUNK
  const int chunk = blockIdx.x & (NCHUNK - 1);
  const int t0    = chunk * CHUNK;

  // ---- load: v[i][j] = in[b, i, t0 + 4*lane + j], coalesced float4 ----
  float v[N_INST][4];
  const size_t base = (size_t)b * N_INST * T_DIM + (size_t)t0 + 4 * lane;
#pragma unroll
  for (int i = 0; i < N_INST; ++i) {
    const float4 q = *reinterpret_cast<const float4*>(in + base + (size_t)i * T_DIM);
    v[i][0] = q.x; v[i][1] = q.y; v[i][2] = q.z; v[i][3] = q.w;
  }

  // ---- pass 1: sparsemax over instruments at each of this lane's 4 times ----
#pragma unroll
  for (int j = 0; j < 4; ++j) {
    float z[N_INST];
#pragma unroll
    for (int i = 0; i < N_INST; ++i) z[i] = v[i][j];
    sort_desc16(z);
    const float tau = sparsemax_tau(z);
#pragma unroll
    for (int i = 0; i < N_INST; ++i) v[i][j] = fmaxf(v[i][j] - tau, 0.0f);
  }

  // ---- stage to LDS, XOR-swizzled so pass-2 row reads are conflict-free ----
  // float index for (inst i, time t): i*CHUNK + (t ^ ((i&7)<<2))
#pragma unroll
  for (int i = 0; i < N_INST; ++i) {
    const int fi = i * CHUNK + ((4 * lane) ^ ((i & 7) << 2));
    *reinterpret_cast<float4*>(&tile[fi]) = make_float4(v[i][0], v[i][1], v[i][2], v[i][3]);
  }
  __syncthreads();

  // ---- pass 2: lane = one (inst, frame) row of 64; order-free gather ----
  const int i2 = lane >> 2;   // inst
  const int f2 = lane & 3;    // frame within chunk
  float w[64];
#pragma unroll
  for (int j = 0; j < 16; ++j) {
    const int fi = i2 * CHUNK + ((f2 * 64 + 4 * j) ^ ((i2 & 7) << 2));
    const float4 q = *reinterpret_cast<const float4*>(&tile[fi]);
    w[4 * j + 0] = q.x; w[4 * j + 1] = q.y; w[4 * j + 2] = q.z; w[4 * j + 3] = q.w;
  }
  sort_desc64(w);
  const float tau2 = sparsemax_tau(w);

  // ---- broadcast row-taus to phase-1 layout; coalesced float4 stores ----
  const int f1 = lane >> 4;   // this lane's frame (4*lane/64)
#pragma unroll
  for (int i = 0; i < N_INST; ++i) {
    const int srclane = i * 4 + f1;   // phase-2 lane holding tau for (i, f1)
    const float taui = __int_as_float(
        __builtin_amdgcn_ds_bpermute(srclane << 2, __float_as_int(tau2)));
    const int fi = i * CHUNK + ((4 * lane) ^ ((i & 7) << 2));
    const float4 q = *reinterpret_cast<const float4*>(&tile[fi]);  // own writes
    float4 o;
    o.x = fmaxf(q.x - taui, 0.0f);
    o.y = fmaxf(q.y - taui, 0.0f);
    o.z = fmaxf(q.z - taui, 0.0f);
    o.w = fmaxf(q.w - taui, 0.0f);
    *reinterpret_cast<float4*>(out + base + (size_t)i * T_DIM) = o;
  }
}

extern "C" void kernel_launch(void* const* d_in, const int* in_sizes, int n_in,
                              void* d_out, int out_size, void* d_ws, size_t ws_size,
                              hipStream_t stream) {
  const float* in = (const float*)d_in[0];
  float* out = (float*)d_out;
  const int grid = B_DIM * NCHUNK;  // 8192 waves, one 16x256 tile each
  seq_sparsemax_kernel<<<grid, 64, 0, stream>>>(in, out);
}